// Round 1
// baseline (41538.068 us; speedup 1.0000x reference)
//
#include <hip/hip_runtime.h>
#include <hip/hip_bf16.h>
#include <math.h>

// ---------------- model dims ----------------
#define Bsz 32
#define Cdim 768
#define Mdim 3072
#define Ldim 12
#define HP 14
#define WP 14
#define Ppix 16
#define NCls 1000
#define NTOK 210            // HP * (WP+1)
#define TTOT (Bsz*NTOK)     // 6720
#define NPATCH (HP*WP)      // 196
#define PROWS (Bsz*NPATCH)  // 6272

// ---------------- GEMM tiles ----------------
#define BM 64
#define BN 64
#define BK 16

enum { EPI_NONE = 0, EPI_PHI = 1, EPI_GELU = 2, EPI_RESID = 3 };

// out[m,n] = sum_k A[m,k]*B[n,k] (+bias[n]) with epilogue.
// A: [M,K] row-major (ld=K), B: [N,K] row-major (ld=K), C: [M,N] (ld=N).
// Batched via blockIdx.z with element strides sA,sB,sC.
template<int EPI, bool HAS_BIAS>
__global__ __launch_bounds__(256)
void gemm_nt(const float* __restrict__ A, const float* __restrict__ B,
             const float* __restrict__ bias, float* __restrict__ C,
             int M, int N, int K, long sA, long sB, long sC)
{
    const int bz = blockIdx.z;
    A += (long)bz * sA; B += (long)bz * sB; C += (long)bz * sC;
    const int m0 = blockIdx.y * BM, n0 = blockIdx.x * BN;

    __shared__ float As[BM][BK + 1];
    __shared__ float Bs[BN][BK + 1];

    const int tid = threadIdx.x;
    const int tx = tid & 15, ty = tid >> 4;
    const int lk = tid & 15;        // k within tile
    const int lmb = tid >> 4;       // 0..15 row base

    float acc[4][4] = {};

    for (int k0 = 0; k0 < K; k0 += BK) {
        #pragma unroll
        for (int p = 0; p < 4; ++p) {
            int r  = lmb + p * 16;          // 0..63
            int gk = k0 + lk;
            int gm = m0 + r;
            As[r][lk] = (gm < M && gk < K) ? A[(long)gm * K + gk] : 0.f;
            int gn = n0 + r;
            Bs[r][lk] = (gn < N && gk < K) ? B[(long)gn * K + gk] : 0.f;
        }
        __syncthreads();
        #pragma unroll
        for (int kk = 0; kk < BK; ++kk) {
            float a[4], b[4];
            #pragma unroll
            for (int i = 0; i < 4; ++i) a[i] = As[ty * 4 + i][kk];
            #pragma unroll
            for (int j = 0; j < 4; ++j) b[j] = Bs[tx * 4 + j][kk];
            #pragma unroll
            for (int i = 0; i < 4; ++i)
                #pragma unroll
                for (int j = 0; j < 4; ++j)
                    acc[i][j] += a[i] * b[j];
        }
        __syncthreads();
    }

    #pragma unroll
    for (int i = 0; i < 4; ++i) {
        int gm = m0 + ty * 4 + i;
        if (gm >= M) continue;
        #pragma unroll
        for (int j = 0; j < 4; ++j) {
            int gn = n0 + tx * 4 + j;
            if (gn >= N) continue;
            float v = acc[i][j];
            if (HAS_BIAS) v += bias[gn];
            long idx = (long)gm * N + gn;
            if (EPI == EPI_PHI)   v = (v > 0.f) ? (v + 1.f) : expf(v);
            if (EPI == EPI_GELU)  v = 0.5f * v * (1.f + erff(v * 0.70710678118654752f));
            if (EPI == EPI_RESID) v += C[idx];
            C[idx] = v;
        }
    }
}

// out[m,n] = sum_k A[k,m]*B[k,n].  A: [K,M] rm (ld=M), B: [K,N] rm (ld=N).
__global__ __launch_bounds__(256)
void gemm_tn(const float* __restrict__ A, const float* __restrict__ B,
             float* __restrict__ C, int M, int N, int K,
             long sA, long sB, long sC)
{
    const int bz = blockIdx.z;
    A += (long)bz * sA; B += (long)bz * sB; C += (long)bz * sC;
    const int m0 = blockIdx.y * BM, n0 = blockIdx.x * BN;

    __shared__ float As[BK][BM];
    __shared__ float Bs[BK][BN];

    const int tid = threadIdx.x;
    const int tx = tid & 15, ty = tid >> 4;
    const int lm = tid & 63;      // col within tile
    const int lkb = tid >> 6;     // 0..3

    float acc[4][4] = {};

    for (int k0 = 0; k0 < K; k0 += BK) {
        #pragma unroll
        for (int p = 0; p < 4; ++p) {
            int kk = lkb * 4 + p;          // 0..15
            int gk = k0 + kk;
            int gm = m0 + lm;
            As[kk][lm] = (gk < K && gm < M) ? A[(long)gk * M + gm] : 0.f;
            int gn = n0 + lm;
            Bs[kk][lm] = (gk < K && gn < N) ? B[(long)gk * N + gn] : 0.f;
        }
        __syncthreads();
        #pragma unroll
        for (int kk = 0; kk < BK; ++kk) {
            float a[4], b[4];
            #pragma unroll
            for (int i = 0; i < 4; ++i) a[i] = As[kk][ty * 4 + i];
            #pragma unroll
            for (int j = 0; j < 4; ++j) b[j] = Bs[kk][tx * 4 + j];
            #pragma unroll
            for (int i = 0; i < 4; ++i)
                #pragma unroll
                for (int j = 0; j < 4; ++j)
                    acc[i][j] += a[i] * b[j];
        }
        __syncthreads();
    }

    #pragma unroll
    for (int i = 0; i < 4; ++i) {
        int gm = m0 + ty * 4 + i;
        if (gm >= M) continue;
        #pragma unroll
        for (int j = 0; j < 4; ++j) {
            int gn = n0 + tx * 4 + j;
            if (gn >= N) continue;
            C[(long)gm * N + gn] = acc[i][j];
        }
    }
}

// LayerNorm over C=768 per row. y = (x-mu)*rsqrt(var+eps)*g + b
__global__ __launch_bounds__(256)
void ln_rows(const float* __restrict__ x, float* __restrict__ y,
             const float* __restrict__ g, const float* __restrict__ bta)
{
    int r = blockIdx.x;
    const float* xr = x + (long)r * Cdim;
    float* yr = y + (long)r * Cdim;
    int t = threadIdx.x;

    float v0 = xr[t], v1 = xr[t + 256], v2 = xr[t + 512];
    float s  = v0 + v1 + v2;
    float s2 = v0 * v0 + v1 * v1 + v2 * v2;
    #pragma unroll
    for (int o = 32; o > 0; o >>= 1) {
        s  += __shfl_down(s,  o, 64);
        s2 += __shfl_down(s2, o, 64);
    }
    __shared__ float sh[4], sh2[4];
    int wid = t >> 6;
    if ((t & 63) == 0) { sh[wid] = s; sh2[wid] = s2; }
    __syncthreads();
    float S  = sh[0] + sh[1] + sh[2] + sh[3];
    float S2 = sh2[0] + sh2[1] + sh2[2] + sh2[3];
    float mu  = S * (1.f / Cdim);
    float var = S2 * (1.f / Cdim) - mu * mu;
    float inv = rsqrtf(var + 1e-5f);
    yr[t]       = (v0 - mu) * inv * g[t]       + bta[t];
    yr[t + 256] = (v1 - mu) * inv * g[t + 256] + bta[t + 256];
    yr[t + 512] = (v2 - mu) * inv * g[t + 512] + bta[t + 512];
}

// im2col for the stride-16 patch conv.
// out[row=(b*196+hp*14+wp)][col=c*256+k*16+l] = x[b,c,hp*16+k,wp*16+l]
__global__ void im2col_patch(const float* __restrict__ x, float* __restrict__ out)
{
    long idx = (long)blockIdx.x * 256 + threadIdx.x;
    if (idx >= (long)PROWS * Cdim) return;
    int col = (int)(idx % Cdim);
    int row = (int)(idx / Cdim);
    int c = col >> 8, rem = col & 255, k = rem >> 4, l = rem & 15;
    int wp = row % 14; int t2 = row / 14; int hp = t2 % 14; int b = t2 / 14;
    out[idx] = x[(((long)b * 3 + c) * 224 + hp * 16 + k) * 224 + wp * 16 + l];
}

// h[b, n=hp*15+w, c] = (w==0 ? cls[c] : pe_ln[b*196+hp*14+w-1, c]) + pos_enc[c,hp,w]
__global__ void assemble_h(const float* __restrict__ pe_ln,
                           const float* __restrict__ cls_tok,
                           const float* __restrict__ pos_enc,
                           float* __restrict__ h)
{
    long idx = (long)blockIdx.x * 256 + threadIdx.x;
    if (idx >= (long)TTOT * Cdim) return;
    int c = (int)(idx % Cdim);
    long t = idx / Cdim;
    int n = (int)(t % NTOK); int b = (int)(t / NTOK);
    int hp = n / 15, w = n % 15;
    float pos = pos_enc[(long)c * (HP * 15) + hp * 15 + w];
    float v;
    if (w == 0) v = cls_tok[c];
    else        v = pe_ln[((long)b * NPATCH + hp * 14 + (w - 1)) * Cdim + c];
    h[idx] = v + pos;
}

// cls_feat[b,c] = mean_hp h[b, hp*15, c]
__global__ void cls_pool(const float* __restrict__ h, float* __restrict__ cf)
{
    int idx = blockIdx.x * 256 + threadIdx.x;
    if (idx >= Bsz * Cdim) return;
    int c = idx % Cdim, b = idx / Cdim;
    float s = 0.f;
    #pragma unroll
    for (int hp = 0; hp < HP; ++hp)
        s += h[((long)b * NTOK + hp * 15) * Cdim + c];
    cf[idx] = s * (1.f / HP);
}

// out[b,j] = cls_feat[b,:] . head_w[j,:] + head_b[j]
__global__ void head_gemm(const float* __restrict__ cf, const float* __restrict__ w,
                          const float* __restrict__ bias, float* __restrict__ out)
{
    int idx = blockIdx.x * 256 + threadIdx.x;
    if (idx >= Bsz * NCls) return;
    int j = idx % NCls, b = idx / NCls;
    const float* cr = cf + (long)b * Cdim;
    const float* wr = w + (long)j * Cdim;
    float s = 0.f;
    for (int c = 0; c < Cdim; ++c) s += cr[c] * wr[c];
    out[idx] = s + bias[j];
}

extern "C" void kernel_launch(void* const* d_in, const int* in_sizes, int n_in,
                              void* d_out, int out_size, void* d_ws, size_t ws_size,
                              hipStream_t stream)
{
    const float* x       = (const float*)d_in[0];
    const float* patch_w = (const float*)d_in[1];
    const float* patch_b = (const float*)d_in[2];
    const float* pe_g    = (const float*)d_in[3];
    const float* pe_b    = (const float*)d_in[4];
    const float* cls_tok = (const float*)d_in[5];
    const float* pos_enc = (const float*)d_in[6];
    const float* Wq      = (const float*)d_in[7];
    const float* Wk      = (const float*)d_in[8];
    const float* Wv      = (const float*)d_in[9];
    const float* Wo_w    = (const float*)d_in[10];
    const float* Wo_b    = (const float*)d_in[11];
    const float* ln1_g   = (const float*)d_in[12];
    const float* ln1_b   = (const float*)d_in[13];
    const float* ln2_g   = (const float*)d_in[14];
    const float* ln2_b   = (const float*)d_in[15];
    const float* mlp1_w  = (const float*)d_in[16];
    const float* mlp1_b  = (const float*)d_in[17];
    const float* mlp2_w  = (const float*)d_in[18];
    const float* mlp2_b  = (const float*)d_in[19];
    const float* head_w  = (const float*)d_in[20];
    const float* head_b  = (const float*)d_in[21];

    // ---- workspace layout (fp32) ----
    const size_t TC  = (size_t)TTOT * Cdim;          // 5,160,960
    const size_t QVS = (size_t)Bsz * Cdim * Cdim;    // 18,874,368
    const size_t HID = (size_t)TTOT * Mdim;          // 20,643,840
    float* ws  = (float*)d_ws;
    float* h   = ws;
    float* xn  = h  + TC;
    float* pq  = xn + TC;
    float* pk  = pq + TC;
    float* pv  = pk + TC;
    float* att = pv + TC;
    float* qv  = att + TC;
    float* hid = qv + QVS;
    float* cf  = hid + HID;
    const size_t need = (6 * TC + QVS + HID + (size_t)Bsz * Cdim) * sizeof(float);
    if (ws_size < need) return;   // workspace too small; nothing sane possible

    float* im  = hid;   // alias: im2col buffer (used only before layer loop)
    float* peo = pq;    // alias: patch-embed conv output
    float* pel = pk;    // alias: patch-embed LN output

    // ---- patch embedding ----
    {
        long tot = (long)PROWS * Cdim;
        im2col_patch<<<dim3((tot + 255) / 256), 256, 0, stream>>>(x, im);
        gemm_nt<EPI_NONE, true><<<dim3(Cdim / BN, PROWS / BM, 1), 256, 0, stream>>>(
            im, patch_w, patch_b, peo, PROWS, Cdim, Cdim, 0, 0, 0);
        ln_rows<<<dim3(PROWS), 256, 0, stream>>>(peo, pel, pe_g, pe_b);
        long tot2 = (long)TTOT * Cdim;
        assemble_h<<<dim3((tot2 + 255) / 256), 256, 0, stream>>>(pel, cls_tok, pos_enc, h);
    }

    // ---- transformer layers ----
    const long CC = (long)Cdim * Cdim;
    for (int l = 0; l < Ldim; ++l) {
        const float* wq  = Wq + (long)l * CC;
        const float* wk  = Wk + (long)l * CC;
        const float* wv  = Wv + (long)l * CC;
        const float* wo  = Wo_w + (long)l * CC;
        const float* wob = Wo_b + (long)l * Cdim;
        const float* g1  = ln1_g + (long)l * Cdim;
        const float* b1  = ln1_b + (long)l * Cdim;
        const float* g2  = ln2_g + (long)l * Cdim;
        const float* b2  = ln2_b + (long)l * Cdim;
        const float* m1w = mlp1_w + (long)l * Mdim * Cdim;
        const float* m1b = mlp1_b + (long)l * Mdim;
        const float* m2w = mlp2_w + (long)l * Cdim * Mdim;
        const float* m2b = mlp2_b + (long)l * Cdim;

        // xn = LN(h; g1,b1)
        ln_rows<<<dim3(TTOT), 256, 0, stream>>>(h, xn, g1, b1);

        // pq/pk/pv = phi(xn @ W^T)
        gemm_nt<EPI_PHI, false><<<dim3(Cdim / BN, TTOT / BM, 1), 256, 0, stream>>>(
            xn, wq, nullptr, pq, TTOT, Cdim, Cdim, 0, 0, 0);
        gemm_nt<EPI_PHI, false><<<dim3(Cdim / BN, TTOT / BM, 1), 256, 0, stream>>>(
            xn, wk, nullptr, pk, TTOT, Cdim, Cdim, 0, 0, 0);
        gemm_nt<EPI_PHI, false><<<dim3(Cdim / BN, TTOT / BM, 1), 256, 0, stream>>>(
            xn, wv, nullptr, pv, TTOT, Cdim, Cdim, 0, 0, 0);

        // qv[b,c,d] = sum_n pq[b,n,c]*pv[b,n,d]   (TN, batched over B)
        gemm_tn<<<dim3(Cdim / BN, Cdim / BM, Bsz), 256, 0, stream>>>(
            pq, pv, qv, Cdim, Cdim, NTOK,
            (long)NTOK * Cdim, (long)NTOK * Cdim, CC);

        // att[b,n,c] = sum_d pk[b,n,d]*qv[b,c,d]  (NT, batched over B)
        gemm_nt<EPI_NONE, false><<<dim3(Cdim / BN, (NTOK + BM - 1) / BM, Bsz), 256, 0, stream>>>(
            pk, qv, nullptr, att, NTOK, Cdim, Cdim,
            (long)NTOK * Cdim, CC, (long)NTOK * Cdim);

        // h += att @ Wo^T + wob
        gemm_nt<EPI_RESID, true><<<dim3(Cdim / BN, TTOT / BM, 1), 256, 0, stream>>>(
            att, wo, wob, h, TTOT, Cdim, Cdim, 0, 0, 0);

        // xn = LN(h; g2,b2)
        ln_rows<<<dim3(TTOT), 256, 0, stream>>>(h, xn, g2, b2);

        // hid = gelu(xn @ mlp1^T + b1)
        gemm_nt<EPI_GELU, true><<<dim3(Mdim / BN, TTOT / BM, 1), 256, 0, stream>>>(
            xn, m1w, m1b, hid, TTOT, Mdim, Cdim, 0, 0, 0);

        // h += hid @ mlp2^T + b2
        gemm_nt<EPI_RESID, true><<<dim3(Cdim / BN, TTOT / BM, 1), 256, 0, stream>>>(
            hid, m2w, m2b, h, TTOT, Cdim, Mdim, 0, 0, 0);
    }

    // ---- head ----
    cls_pool<<<dim3((Bsz * Cdim + 255) / 256), 256, 0, stream>>>(h, cf);
    head_gemm<<<dim3((Bsz * NCls + 255) / 256), 256, 0, stream>>>(
        cf, head_w, head_b, (float*)d_out);
}

// Round 2
// 4685.862 us; speedup vs baseline: 8.8646x; 8.8646x over previous
//
#include <hip/hip_runtime.h>
#include <hip/hip_bf16.h>
#include <math.h>

// ---------------- model dims ----------------
#define Bsz 32
#define Cdim 768
#define Mdim 3072
#define Ldim 12
#define NTOK 210            // real tokens per image: 14*(14+1)
#define NTOKP 256           // padded tokens per image (div by 128)
#define TPAD (Bsz*NTOKP)    // 8192 padded token rows
#define NPATCH 196
#define PROWS (Bsz*NPATCH)  // 6272 = 49*128
#define NCls 1000

typedef __hip_bfloat16 bf16;
typedef __attribute__((ext_vector_type(8))) short bfrag;   // 8 bf16 = 4 VGPR
typedef __attribute__((ext_vector_type(4))) float f32x4;

enum { EPI_NONE = 0, EPI_PHI = 1, EPI_GELU = 2, EPI_RESID = 3 };

__device__ __forceinline__ void gl_lds16(const void* g, void* l) {
    __builtin_amdgcn_global_load_lds(
        (const __attribute__((address_space(1))) unsigned*)g,
        (__attribute__((address_space(3))) unsigned*)l, 16, 0, 0);
}

__device__ __forceinline__ void stv(float* p, float v) { *p = v; }
__device__ __forceinline__ void stv(bf16* p, float v)  { *p = __float2bfloat16(v); }

// -------------------------------------------------------------------------
// MFMA NT-GEMM (m97 structure): C[m,n] = sum_k A[m,k]*B[n,k] (+bias) +epi.
// A:[M,K] bf16 rm, B:[N,K] bf16 rm, C:[M,N] OUTT. Batched via blockIdx.z.
// M%128==0, N%128==0, K%32==0 guaranteed by caller (padded layouts).
// zc: for EPI_PHI only — output cols gn>=zc are written as 0 (token pad).
// -------------------------------------------------------------------------
template<int EPI, bool HAS_BIAS, typename OUTT>
__global__ __launch_bounds__(256)
void gemm_bt(const bf16* __restrict__ A, const bf16* __restrict__ B,
             const float* __restrict__ bias, OUTT* __restrict__ C,
             int M, int N, int K, long sA, long sB, long sC, int zc)
{
    const int bz = blockIdx.z;
    A += (long)bz * sA; B += (long)bz * sB; C += (long)bz * sC;
    const int m0 = blockIdx.y * 128, n0 = blockIdx.x * 128;

    __shared__ __align__(16) bf16 As[128 * 32];
    __shared__ __align__(16) bf16 Bs[128 * 32];

    const int tid  = threadIdx.x;
    const int lane = tid & 63, wid = tid >> 6;
    const int wr = wid >> 1, wc = wid & 1;

    f32x4 acc[4][4];
    #pragma unroll
    for (int i = 0; i < 4; ++i)
        #pragma unroll
        for (int j = 0; j < 4; ++j)
            acc[i][j] = f32x4{0.f, 0.f, 0.f, 0.f};

    // staging: 256 threads x 16B x 2 passes per 128x32 bf16 tile
    const int srow = tid >> 2;            // 0..63
    const int scol = (tid & 3) * 8;       // 0,8,16,24
    const bf16* gA = A + (long)(m0 + srow) * K + scol;
    const bf16* gB = B + (long)(n0 + srow) * K + scol;

    const int lr = lane & 15, lg = lane >> 4;
    const int aoff0 = (wr * 64 + lr) * 32 + lg * 8;
    const int boff0 = (wc * 64 + lr) * 32 + lg * 8;

    for (int k0 = 0; k0 < K; k0 += 32) {
        gl_lds16(gA,               &As[tid * 8]);
        gl_lds16(gA + (long)64 * K, &As[2048 + tid * 8]);
        gl_lds16(gB,               &Bs[tid * 8]);
        gl_lds16(gB + (long)64 * K, &Bs[2048 + tid * 8]);
        gA += 32; gB += 32;
        asm volatile("s_waitcnt vmcnt(0)" ::: "memory");
        __syncthreads();

        bfrag a[4], b[4];
        #pragma unroll
        for (int i = 0; i < 4; ++i) a[i] = *(const bfrag*)&As[aoff0 + i * 16 * 32];
        #pragma unroll
        for (int j = 0; j < 4; ++j) b[j] = *(const bfrag*)&Bs[boff0 + j * 16 * 32];
        #pragma unroll
        for (int i = 0; i < 4; ++i)
            #pragma unroll
            for (int j = 0; j < 4; ++j)
                acc[i][j] = __builtin_amdgcn_mfma_f32_16x16x32_bf16(a[i], b[j], acc[i][j], 0, 0, 0);
        __syncthreads();
    }

    // epilogue: C/D mapping col=lane&15, row=(lane>>4)*4+reg  [m89/m91]
    const int cidx  = lane & 15;
    const int rbase = (lane >> 4) * 4;
    #pragma unroll
    for (int i = 0; i < 4; ++i) {
        #pragma unroll
        for (int j = 0; j < 4; ++j) {
            const int gn = n0 + wc * 64 + j * 16 + cidx;
            float bv = HAS_BIAS ? bias[gn] : 0.f;
            #pragma unroll
            for (int r = 0; r < 4; ++r) {
                const int gm = m0 + wr * 64 + i * 16 + rbase + r;
                float v = acc[i][j][r] + bv;
                long idx = (long)gm * N + gn;
                if (EPI == EPI_PHI) {
                    v = (v > 0.f) ? (v + 1.f) : expf(v);
                    if (gn >= zc) v = 0.f;           // zero token-pad cols
                }
                if (EPI == EPI_GELU)  v = 0.5f * v * (1.f + erff(v * 0.70710678118654752f));
                if (EPI == EPI_RESID) v += ((const float*)C)[idx];
                stv(&C[idx], v);
            }
        }
    }
}

// ---------------- LayerNorm over C=768 per row ----------------
template<typename OUTT>
__global__ __launch_bounds__(256)
void ln_rows(const float* __restrict__ x, OUTT* __restrict__ y,
             const float* __restrict__ g, const float* __restrict__ bta)
{
    int r = blockIdx.x;
    const float* xr = x + (long)r * Cdim;
    OUTT* yr = y + (long)r * Cdim;
    int t = threadIdx.x;

    float v0 = xr[t], v1 = xr[t + 256], v2 = xr[t + 512];
    float s  = v0 + v1 + v2;
    float s2 = v0 * v0 + v1 * v1 + v2 * v2;
    #pragma unroll
    for (int o = 32; o > 0; o >>= 1) {
        s  += __shfl_down(s,  o, 64);
        s2 += __shfl_down(s2, o, 64);
    }
    __shared__ float sh[4], sh2[4];
    int wid = t >> 6;
    if ((t & 63) == 0) { sh[wid] = s; sh2[wid] = s2; }
    __syncthreads();
    float S  = sh[0] + sh[1] + sh[2] + sh[3];
    float S2 = sh2[0] + sh2[1] + sh2[2] + sh2[3];
    float mu  = S * (1.f / Cdim);
    float var = S2 * (1.f / Cdim) - mu * mu;
    float inv = rsqrtf(var + 1e-5f);
    stv(&yr[t],       (v0 - mu) * inv * g[t]       + bta[t]);
    stv(&yr[t + 256], (v1 - mu) * inv * g[t + 256] + bta[t + 256]);
    stv(&yr[t + 512], (v2 - mu) * inv * g[t + 512] + bta[t + 512]);
}

// ---------------- fp32 -> bf16 cast (8 elems/thread) ----------------
__global__ void cast_f2b(const float* __restrict__ in, bf16* __restrict__ out, long n)
{
    long i = ((long)blockIdx.x * 256 + threadIdx.x) * 8;
    if (i >= n) return;
    float4 v0 = *(const float4*)(in + i);
    float4 v1 = *(const float4*)(in + i + 4);
    union { bf16 b[8]; uint4 u; } t;
    t.b[0] = __float2bfloat16(v0.x); t.b[1] = __float2bfloat16(v0.y);
    t.b[2] = __float2bfloat16(v0.z); t.b[3] = __float2bfloat16(v0.w);
    t.b[4] = __float2bfloat16(v1.x); t.b[5] = __float2bfloat16(v1.y);
    t.b[6] = __float2bfloat16(v1.z); t.b[7] = __float2bfloat16(v1.w);
    *(uint4*)(out + i) = t.u;
}

// ---------------- im2col (bf16 out) for stride-16 patch conv ----------------
__global__ void im2col_patch(const float* __restrict__ x, bf16* __restrict__ out)
{
    long idx = (long)blockIdx.x * 256 + threadIdx.x;
    if (idx >= (long)PROWS * Cdim) return;
    int col = (int)(idx % Cdim);
    int row = (int)(idx / Cdim);
    int c = col >> 8, rem = col & 255, k = rem >> 4, l = rem & 15;
    int wp = row % 14; int t2 = row / 14; int hp = t2 % 14; int b = t2 / 14;
    out[idx] = __float2bfloat16(x[(((long)b * 3 + c) * 224 + hp * 16 + k) * 224 + wp * 16 + l]);
}

// h[b*256+n, c]: n<210 -> token value + pos_enc; n>=210 -> 0
__global__ void assemble_h(const float* __restrict__ pel,
                           const float* __restrict__ cls_tok,
                           const float* __restrict__ pos_enc,
                           float* __restrict__ h)
{
    long idx = (long)blockIdx.x * 256 + threadIdx.x;
    if (idx >= (long)TPAD * Cdim) return;
    int c = (int)(idx % Cdim);
    long t = idx / Cdim;
    int n = (int)(t % NTOKP); int b = (int)(t / NTOKP);
    if (n >= NTOK) { h[idx] = 0.f; return; }
    int hp = n / 15, w = n % 15;
    float pos = pos_enc[(long)c * NTOK + hp * 15 + w];
    float v = (w == 0) ? cls_tok[c]
                       : pel[((long)b * NPATCH + hp * 14 + (w - 1)) * Cdim + c];
    h[idx] = v + pos;
}

// cls_feat[b,c] = mean_hp h[b*256 + hp*15, c]
__global__ void cls_pool(const float* __restrict__ h, float* __restrict__ cf)
{
    int idx = blockIdx.x * 256 + threadIdx.x;
    if (idx >= Bsz * Cdim) return;
    int c = idx % Cdim, b = idx / Cdim;
    float s = 0.f;
    #pragma unroll
    for (int hp = 0; hp < 14; ++hp)
        s += h[((long)b * NTOKP + hp * 15) * Cdim + c];
    cf[idx] = s * (1.f / 14.f);
}

__global__ void head_gemm(const float* __restrict__ cf, const float* __restrict__ w,
                          const float* __restrict__ bias, float* __restrict__ out)
{
    int idx = blockIdx.x * 256 + threadIdx.x;
    if (idx >= Bsz * NCls) return;
    int j = idx % NCls, b = idx / NCls;
    const float* cr = cf + (long)b * Cdim;
    const float* wr = w + (long)j * Cdim;
    float s = 0.f;
    for (int c = 0; c < Cdim; ++c) s += cr[c] * wr[c];
    out[idx] = s + bias[j];
}

// -------------------------------------------------------------------------
extern "C" void kernel_launch(void* const* d_in, const int* in_sizes, int n_in,
                              void* d_out, int out_size, void* d_ws, size_t ws_size,
                              hipStream_t stream)
{
    const float* x       = (const float*)d_in[0];
    const float* patch_w = (const float*)d_in[1];
    const float* patch_b = (const float*)d_in[2];
    const float* pe_g    = (const float*)d_in[3];
    const float* pe_b    = (const float*)d_in[4];
    const float* cls_tok = (const float*)d_in[5];
    const float* pos_enc = (const float*)d_in[6];
    const float* Wq      = (const float*)d_in[7];
    const float* Wk      = (const float*)d_in[8];
    const float* Wv      = (const float*)d_in[9];
    const float* Wo_w    = (const float*)d_in[10];
    const float* Wo_b    = (const float*)d_in[11];
    const float* ln1_g   = (const float*)d_in[12];
    const float* ln1_b   = (const float*)d_in[13];
    const float* ln2_g   = (const float*)d_in[14];
    const float* ln2_b   = (const float*)d_in[15];
    const float* mlp1_w  = (const float*)d_in[16];
    const float* mlp1_b  = (const float*)d_in[17];
    const float* mlp2_w  = (const float*)d_in[18];
    const float* mlp2_b  = (const float*)d_in[19];
    const float* head_w  = (const float*)d_in[20];
    const float* head_b  = (const float*)d_in[21];

    // ---------------- workspace layout ----------------
    char* base = (char*)d_ws;
    size_t off = 0;
    auto take = [&](size_t bytes) -> char* {
        char* p = base + off; off += (bytes + 255) & ~(size_t)255; return p;
    };
    float* h   = (float*)take((size_t)TPAD * Cdim * 4);          // fp32 residual
    bf16*  xn  = (bf16*) take((size_t)TPAD * Cdim * 2);
    bf16*  pk  = (bf16*) take((size_t)TPAD * Cdim * 2);
    bf16*  pqT = (bf16*) take((size_t)Bsz * Cdim * NTOKP * 2);   // [B][C][256]
    bf16*  pvT = (bf16*) take((size_t)Bsz * Cdim * NTOKP * 2);
    char*  big = take((size_t)TPAD * Mdim * 2);                  // 50.3 MB shared region
    bf16*  wbf = (bf16*) take((size_t)85524480 * 2);             // bf16 weights
    if (off > ws_size) return;

    // big-region aliases (phase-disjoint)
    bf16*  hid = (bf16*)big;                                         // MLP phase
    bf16*  qv  = (bf16*)big;                                         // attn phase [B][768][768]
    bf16*  att = (bf16*)(big + (size_t)Bsz * Cdim * Cdim * 2);       // attn phase
    bf16*  im  = (bf16*)big;                                         // patch phase
    float* peo = (float*)(big + 9633792);
    float* pel = (float*)(big + 9633792 + 19267584);
    float* cf  = (float*)big;                                        // head phase

    // bf16 weight sub-buffers
    const long nCC = (long)Ldim * Cdim * Cdim;      // 7,077,888
    const long nMC = (long)Ldim * Mdim * Cdim;      // 28,311,552
    bf16* wq_bf = wbf;
    bf16* wk_bf = wq_bf + nCC;
    bf16* wv_bf = wk_bf + nCC;
    bf16* wo_bf = wv_bf + nCC;
    bf16* m1_bf = wo_bf + nCC;
    bf16* m2_bf = m1_bf + nMC;
    bf16* pw_bf = m2_bf + nMC;

    auto cast = [&](const float* src, bf16* dst, long n) {
        cast_f2b<<<dim3((unsigned)((n / 8 + 255) / 256)), 256, 0, stream>>>(src, dst, n);
    };
    cast(Wq, wq_bf, nCC);  cast(Wk, wk_bf, nCC);  cast(Wv, wv_bf, nCC);
    cast(Wo_w, wo_bf, nCC); cast(mlp1_w, m1_bf, nMC); cast(mlp2_w, m2_bf, nMC);
    cast(patch_w, pw_bf, (long)Cdim * Cdim);

    // ---------------- patch embedding ----------------
    {
        long tot = (long)PROWS * Cdim;
        im2col_patch<<<dim3((unsigned)((tot + 255) / 256)), 256, 0, stream>>>(x, im);
        gemm_bt<EPI_NONE, true, float><<<dim3(6, 49, 1), 256, 0, stream>>>(
            im, pw_bf, patch_b, peo, PROWS, Cdim, Cdim, 0, 0, 0, 0);
        ln_rows<float><<<dim3(PROWS), 256, 0, stream>>>(peo, pel, pe_g, pe_b);
        long tot2 = (long)TPAD * Cdim;
        assemble_h<<<dim3((unsigned)((tot2 + 255) / 256)), 256, 0, stream>>>(
            pel, cls_tok, pos_enc, h);
    }

    // ---------------- transformer layers ----------------
    const long CC = (long)Cdim * Cdim;
    const long TNC = (long)NTOKP * Cdim;            // per-batch activation stride
    for (int l = 0; l < Ldim; ++l) {
        const bf16*  wq  = wq_bf + (long)l * CC;
        const bf16*  wk  = wk_bf + (long)l * CC;
        const bf16*  wv  = wv_bf + (long)l * CC;
        const bf16*  wo  = wo_bf + (long)l * CC;
        const bf16*  m1  = m1_bf + (long)l * Mdim * Cdim;
        const bf16*  m2  = m2_bf + (long)l * Mdim * Cdim;
        const float* wob = Wo_b  + (long)l * Cdim;
        const float* g1  = ln1_g + (long)l * Cdim;
        const float* b1  = ln1_b + (long)l * Cdim;
        const float* g2  = ln2_g + (long)l * Cdim;
        const float* b2  = ln2_b + (long)l * Cdim;
        const float* m1b = mlp1_b + (long)l * Mdim;
        const float* m2b = mlp2_b + (long)l * Cdim;

        ln_rows<bf16><<<dim3(TPAD), 256, 0, stream>>>(h, xn, g1, b1);

        // pqT[b][c][n] = phi(sum_k wq[c,k]*xn[b,n,k]); pad cols zeroed
        gemm_bt<EPI_PHI, false, bf16><<<dim3(2, 6, Bsz), 256, 0, stream>>>(
            wq, xn, nullptr, pqT, Cdim, NTOKP, Cdim, 0, TNC, TNC, NTOK);
        gemm_bt<EPI_PHI, false, bf16><<<dim3(2, 6, Bsz), 256, 0, stream>>>(
            wv, xn, nullptr, pvT, Cdim, NTOKP, Cdim, 0, TNC, TNC, NTOK);
        // pk[t][d] = phi(sum_k xn[t,k]*wk[d,k])
        gemm_bt<EPI_PHI, false, bf16><<<dim3(6, TPAD / 128, 1), 256, 0, stream>>>(
            xn, wk, nullptr, pk, TPAD, Cdim, Cdim, 0, 0, 0, 1 << 30);

        // qv[b][c][d] = sum_n pqT[b,c,n]*pvT[b,d,n]
        gemm_bt<EPI_NONE, false, bf16><<<dim3(6, 6, Bsz), 256, 0, stream>>>(
            pqT, pvT, nullptr, qv, Cdim, Cdim, NTOKP, TNC, TNC, CC, 0);
        // att[b][n][c] = sum_d pk[b,n,d]*qv[b,c,d]
        gemm_bt<EPI_NONE, false, bf16><<<dim3(6, 2, Bsz), 256, 0, stream>>>(
            pk, qv, nullptr, att, NTOKP, Cdim, Cdim, TNC, CC, TNC, 0);
        // h += att @ wo^T + wob
        gemm_bt<EPI_RESID, true, float><<<dim3(6, TPAD / 128, 1), 256, 0, stream>>>(
            att, wo, wob, h, TPAD, Cdim, Cdim, 0, 0, 0, 0);

        ln_rows<bf16><<<dim3(TPAD), 256, 0, stream>>>(h, xn, g2, b2);

        // hid = gelu(xn @ m1^T + m1b)
        gemm_bt<EPI_GELU, true, bf16><<<dim3(Mdim / 128, TPAD / 128, 1), 256, 0, stream>>>(
            xn, m1, m1b, hid, TPAD, Mdim, Cdim, 0, 0, 0, 0);
        // h += hid @ m2^T + m2b
        gemm_bt<EPI_RESID, true, float><<<dim3(6, TPAD / 128, 1), 256, 0, stream>>>(
            hid, m2, m2b, h, TPAD, Cdim, Mdim, 0, 0, 0, 0);
    }

    // ---------------- head ----------------
    cls_pool<<<dim3((Bsz * Cdim + 255) / 256), 256, 0, stream>>>(h, cf);
    head_gemm<<<dim3((Bsz * NCls + 255) / 256), 256, 0, stream>>>(
        cf, head_w, head_b, (float*)d_out);
}

// Round 3
// 3920.535 us; speedup vs baseline: 10.5950x; 1.1952x over previous
//
#include <hip/hip_runtime.h>
#include <hip/hip_bf16.h>
#include <math.h>

// ---------------- model dims ----------------
#define Bsz 32
#define Cdim 768
#define Mdim 3072
#define Ldim 12
#define NTOK 210            // real tokens per image: 14*(14+1)
#define NTOKP 256           // padded tokens per image (div by 128)
#define TPAD (Bsz*NTOKP)    // 8192 padded token rows
#define NPATCH 196
#define PROWS (Bsz*NPATCH)  // 6272 = 49*128
#define NCls 1000

typedef __hip_bfloat16 bf16;
typedef __attribute__((ext_vector_type(8))) short bfrag;   // 8 bf16 = 4 VGPR
typedef __attribute__((ext_vector_type(4))) float f32x4;

enum { EPI_NONE = 0, EPI_PHI = 1, EPI_GELU = 2, EPI_RESID = 3 };

__device__ __forceinline__ void gl_lds16(const void* g, void* l) {
    __builtin_amdgcn_global_load_lds(
        (const __attribute__((address_space(1))) unsigned*)g,
        (__attribute__((address_space(3))) unsigned*)l, 16, 0, 0);
}

__device__ __forceinline__ void stv(float* p, float v) { *p = v; }
__device__ __forceinline__ void stv(bf16* p, float v)  { *p = __float2bfloat16(v); }

// -------------------------------------------------------------------------
// MFMA NT-GEMM, 128x128 tile, BK=32, double-buffered LDS (T3-minimum 2ph):
//   stage(t+1) issued BEFORE compute(t); one vmcnt(0)+barrier per K-step
//   placed AFTER the MFMAs so HBM/L2 latency hides under compute.
// XCD-aware bijective block swizzle (T1/m204) on the flattened grid.
// C[m,n] = sum_k A[m,k]*B[n,k] (+bias) + epilogue. Batched via blockIdx.z.
// M%128==0, N%128==0, K%32==0 guaranteed by caller.
// zc: for EPI_PHI — output cols gn>=zc written as 0 (token pad).
// -------------------------------------------------------------------------
template<int EPI, bool HAS_BIAS, typename OUTT>
__global__ __launch_bounds__(256)
void gemm_bt(const bf16* __restrict__ A, const bf16* __restrict__ B,
             const float* __restrict__ bias, OUTT* __restrict__ C,
             int M, int N, int K, long sA, long sB, long sC, int zc)
{
    // ---- XCD-aware bijective swizzle over the flattened grid ----
    const int gx = gridDim.x, gy = gridDim.y;
    const int nwg = gx * gy * gridDim.z;
    int flat = (blockIdx.z * gy + blockIdx.y) * gx + blockIdx.x;
    {
        int q8 = nwg >> 3, r8 = nwg & 7;
        int xcd = flat & 7, loc = flat >> 3;
        flat = ((xcd < r8) ? xcd * (q8 + 1) : r8 * (q8 + 1) + (xcd - r8) * q8) + loc;
    }
    const int bx = flat % gx;
    const int tmp = flat / gx;
    const int by = tmp % gy;
    const int bz = tmp / gy;

    A += (long)bz * sA; B += (long)bz * sB; C += (long)bz * sC;
    const int m0 = by * 128, n0 = bx * 128;

    __shared__ __align__(16) bf16 As[2][128 * 32];
    __shared__ __align__(16) bf16 Bs[2][128 * 32];

    const int tid  = threadIdx.x;
    const int lane = tid & 63, wid = tid >> 6;
    const int wr = wid >> 1, wc = wid & 1;

    f32x4 acc[4][4];
    #pragma unroll
    for (int i = 0; i < 4; ++i)
        #pragma unroll
        for (int j = 0; j < 4; ++j)
            acc[i][j] = f32x4{0.f, 0.f, 0.f, 0.f};

    // staging: 256 threads x 16B x 2 halves per 128x32 bf16 tile (A and B)
    const int srow = tid >> 2;            // 0..63
    const int scol = (tid & 3) * 8;       // 0,8,16,24
    const bf16* gA = A + (long)(m0 + srow) * K + scol;
    const bf16* gB = B + (long)(n0 + srow) * K + scol;

    const int lr = lane & 15, lg = lane >> 4;
    const int aoff0 = (wr * 64 + lr) * 32 + lg * 8;
    const int boff0 = (wc * 64 + lr) * 32 + lg * 8;

    auto stage = [&](int bufi) {
        gl_lds16(gA,                 &As[bufi][tid * 8]);
        gl_lds16(gA + (long)64 * K,  &As[bufi][2048 + tid * 8]);
        gl_lds16(gB,                 &Bs[bufi][tid * 8]);
        gl_lds16(gB + (long)64 * K,  &Bs[bufi][2048 + tid * 8]);
        gA += 32; gB += 32;
    };

    // prologue
    stage(0);
    asm volatile("s_waitcnt vmcnt(0)" ::: "memory");
    __syncthreads();

    const int kt = K >> 5;
    int buf = 0;
    for (int t = 0; t < kt; ++t) {
        if (t + 1 < kt) stage(buf ^ 1);      // prefetch next tile (async)

        const bf16* Ab = &As[buf][0];
        const bf16* Bb = &Bs[buf][0];
        bfrag a[4], b[4];
        #pragma unroll
        for (int i = 0; i < 4; ++i) a[i] = *(const bfrag*)(Ab + aoff0 + i * 512);
        #pragma unroll
        for (int j = 0; j < 4; ++j) b[j] = *(const bfrag*)(Bb + boff0 + j * 512);
        #pragma unroll
        for (int i = 0; i < 4; ++i)
            #pragma unroll
            for (int j = 0; j < 4; ++j)
                acc[i][j] = __builtin_amdgcn_mfma_f32_16x16x32_bf16(a[i], b[j], acc[i][j], 0, 0, 0);

        if (t + 1 < kt) {
            asm volatile("s_waitcnt vmcnt(0)" ::: "memory");  // prefetch landed
            __syncthreads();
            buf ^= 1;
        }
    }

    // epilogue: C/D mapping col=lane&15, row=(lane>>4)*4+reg  [m89/m91]
    const int cidx  = lane & 15;
    const int rbase = (lane >> 4) * 4;
    #pragma unroll
    for (int i = 0; i < 4; ++i) {
        #pragma unroll
        for (int j = 0; j < 4; ++j) {
            const int gn = n0 + wc * 64 + j * 16 + cidx;
            float bv = HAS_BIAS ? bias[gn] : 0.f;
            #pragma unroll
            for (int r = 0; r < 4; ++r) {
                const int gm = m0 + wr * 64 + i * 16 + rbase + r;
                float v = acc[i][j][r] + bv;
                long idx = (long)gm * N + gn;
                if (EPI == EPI_PHI) {
                    v = (v > 0.f) ? (v + 1.f) : expf(v);
                    if (gn >= zc) v = 0.f;           // zero token-pad cols
                }
                if (EPI == EPI_GELU)  v = 0.5f * v * (1.f + erff(v * 0.70710678118654752f));
                if (EPI == EPI_RESID) v += ((const float*)C)[idx];
                stv(&C[idx], v);
            }
        }
    }
}

// ---------------- LayerNorm over C=768 per row ----------------
template<typename OUTT>
__global__ __launch_bounds__(256)
void ln_rows(const float* __restrict__ x, OUTT* __restrict__ y,
             const float* __restrict__ g, const float* __restrict__ bta)
{
    int r = blockIdx.x;
    const float* xr = x + (long)r * Cdim;
    OUTT* yr = y + (long)r * Cdim;
    int t = threadIdx.x;

    float v0 = xr[t], v1 = xr[t + 256], v2 = xr[t + 512];
    float s  = v0 + v1 + v2;
    float s2 = v0 * v0 + v1 * v1 + v2 * v2;
    #pragma unroll
    for (int o = 32; o > 0; o >>= 1) {
        s  += __shfl_down(s,  o, 64);
        s2 += __shfl_down(s2, o, 64);
    }
    __shared__ float sh[4], sh2[4];
    int wid = t >> 6;
    if ((t & 63) == 0) { sh[wid] = s; sh2[wid] = s2; }
    __syncthreads();
    float S  = sh[0] + sh[1] + sh[2] + sh[3];
    float S2 = sh2[0] + sh2[1] + sh2[2] + sh2[3];
    float mu  = S * (1.f / Cdim);
    float var = S2 * (1.f / Cdim) - mu * mu;
    float inv = rsqrtf(var + 1e-5f);
    stv(&yr[t],       (v0 - mu) * inv * g[t]       + bta[t]);
    stv(&yr[t + 256], (v1 - mu) * inv * g[t + 256] + bta[t + 256]);
    stv(&yr[t + 512], (v2 - mu) * inv * g[t + 512] + bta[t + 512]);
}

// ---------------- fp32 -> bf16 cast (8 elems/thread) ----------------
__global__ void cast_f2b(const float* __restrict__ in, bf16* __restrict__ out, long n)
{
    long i = ((long)blockIdx.x * 256 + threadIdx.x) * 8;
    if (i >= n) return;
    float4 v0 = *(const float4*)(in + i);
    float4 v1 = *(const float4*)(in + i + 4);
    union { bf16 b[8]; uint4 u; } t;
    t.b[0] = __float2bfloat16(v0.x); t.b[1] = __float2bfloat16(v0.y);
    t.b[2] = __float2bfloat16(v0.z); t.b[3] = __float2bfloat16(v0.w);
    t.b[4] = __float2bfloat16(v1.x); t.b[5] = __float2bfloat16(v1.y);
    t.b[6] = __float2bfloat16(v1.z); t.b[7] = __float2bfloat16(v1.w);
    *(uint4*)(out + i) = t.u;
}

// interleaved cast: dst layout per layer l = [Wq(l) CC][Wv(l) CC]
#define CCn (768*768)
__global__ void cast_qv(const float* __restrict__ Wq, const float* __restrict__ Wv,
                        bf16* __restrict__ dst)
{
    long i = ((long)blockIdx.x * 256 + threadIdx.x) * 8;
    if (i >= (long)Ldim * 2 * CCn) return;
    long l = i / (2 * CCn); long rem = i - l * 2 * CCn;
    const float* src = (rem < CCn) ? (Wq + l * CCn + rem) : (Wv + l * CCn + rem - CCn);
    float4 v0 = *(const float4*)(src);
    float4 v1 = *(const float4*)(src + 4);
    union { bf16 b[8]; uint4 u; } t;
    t.b[0] = __float2bfloat16(v0.x); t.b[1] = __float2bfloat16(v0.y);
    t.b[2] = __float2bfloat16(v0.z); t.b[3] = __float2bfloat16(v0.w);
    t.b[4] = __float2bfloat16(v1.x); t.b[5] = __float2bfloat16(v1.y);
    t.b[6] = __float2bfloat16(v1.z); t.b[7] = __float2bfloat16(v1.w);
    *(uint4*)(dst + i) = t.u;
}

// ---------------- im2col (bf16 out) for stride-16 patch conv ----------------
__global__ void im2col_patch(const float* __restrict__ x, bf16* __restrict__ out)
{
    long idx = (long)blockIdx.x * 256 + threadIdx.x;
    if (idx >= (long)PROWS * Cdim) return;
    int col = (int)(idx % Cdim);
    int row = (int)(idx / Cdim);
    int c = col >> 8, rem = col & 255, k = rem >> 4, l = rem & 15;
    int wp = row % 14; int t2 = row / 14; int hp = t2 % 14; int b = t2 / 14;
    out[idx] = __float2bfloat16(x[(((long)b * 3 + c) * 224 + hp * 16 + k) * 224 + wp * 16 + l]);
}

// h[b*256+n, c]: n<210 -> token value + pos_enc; n>=210 -> 0
__global__ void assemble_h(const float* __restrict__ pel,
                           const float* __restrict__ cls_tok,
                           const float* __restrict__ pos_enc,
                           float* __restrict__ h)
{
    long idx = (long)blockIdx.x * 256 + threadIdx.x;
    if (idx >= (long)TPAD * Cdim) return;
    int c = (int)(idx % Cdim);
    long t = idx / Cdim;
    int n = (int)(t % NTOKP); int b = (int)(t / NTOKP);
    if (n >= NTOK) { h[idx] = 0.f; return; }
    int hp = n / 15, w = n % 15;
    float pos = pos_enc[(long)c * NTOK + hp * 15 + w];
    float v = (w == 0) ? cls_tok[c]
                       : pel[((long)b * NPATCH + hp * 14 + (w - 1)) * Cdim + c];
    h[idx] = v + pos;
}

// cls_feat[b,c] = mean_hp h[b*256 + hp*15, c]
__global__ void cls_pool(const float* __restrict__ h, float* __restrict__ cf)
{
    int idx = blockIdx.x * 256 + threadIdx.x;
    if (idx >= Bsz * Cdim) return;
    int c = idx % Cdim, b = idx / Cdim;
    float s = 0.f;
    #pragma unroll
    for (int hp = 0; hp < 14; ++hp)
        s += h[((long)b * NTOKP + hp * 15) * Cdim + c];
    cf[idx] = s * (1.f / 14.f);
}

__global__ void head_gemm(const float* __restrict__ cf, const float* __restrict__ w,
                          const float* __restrict__ bias, float* __restrict__ out)
{
    int idx = blockIdx.x * 256 + threadIdx.x;
    if (idx >= Bsz * NCls) return;
    int j = idx % NCls, b = idx / NCls;
    const float* cr = cf + (long)b * Cdim;
    const float* wr = w + (long)j * Cdim;
    float s = 0.f;
    for (int c = 0; c < Cdim; ++c) s += cr[c] * wr[c];
    out[idx] = s + bias[j];
}

// -------------------------------------------------------------------------
extern "C" void kernel_launch(void* const* d_in, const int* in_sizes, int n_in,
                              void* d_out, int out_size, void* d_ws, size_t ws_size,
                              hipStream_t stream)
{
    const float* x       = (const float*)d_in[0];
    const float* patch_w = (const float*)d_in[1];
    const float* patch_b = (const float*)d_in[2];
    const float* pe_g    = (const float*)d_in[3];
    const float* pe_b    = (const float*)d_in[4];
    const float* cls_tok = (const float*)d_in[5];
    const float* pos_enc = (const float*)d_in[6];
    const float* Wq      = (const float*)d_in[7];
    const float* Wk      = (const float*)d_in[8];
    const float* Wv      = (const float*)d_in[9];
    const float* Wo_w    = (const float*)d_in[10];
    const float* Wo_b    = (const float*)d_in[11];
    const float* ln1_g   = (const float*)d_in[12];
    const float* ln1_b   = (const float*)d_in[13];
    const float* ln2_g   = (const float*)d_in[14];
    const float* ln2_b   = (const float*)d_in[15];
    const float* mlp1_w  = (const float*)d_in[16];
    const float* mlp1_b  = (const float*)d_in[17];
    const float* mlp2_w  = (const float*)d_in[18];
    const float* mlp2_b  = (const float*)d_in[19];
    const float* head_w  = (const float*)d_in[20];
    const float* head_b  = (const float*)d_in[21];

    // ---------------- workspace layout ----------------
    char* base = (char*)d_ws;
    size_t off = 0;
    auto take = [&](size_t bytes) -> char* {
        char* p = base + off; off += (bytes + 255) & ~(size_t)255; return p;
    };
    float* h    = (float*)take((size_t)TPAD * Cdim * 4);           // fp32 residual
    bf16*  xn   = (bf16*) take((size_t)TPAD * Cdim * 2);
    bf16*  pk   = (bf16*) take((size_t)TPAD * Cdim * 2);
    bf16*  pqvT = (bf16*) take((size_t)Bsz * 1536 * NTOKP * 2);    // [B][q0..767,v768..1535][256]
    char*  big  = take((size_t)TPAD * Mdim * 2);                   // 50.3 MB shared region
    bf16*  wbf  = (bf16*) take((size_t)85524480 * 2);              // bf16 weights
    if (off > ws_size) return;

    // big-region aliases (phase-disjoint)
    bf16*  hid = (bf16*)big;                                       // MLP phase
    bf16*  qv  = (bf16*)big;                                       // attn phase [B][768][768]
    bf16*  att = (bf16*)(big + (size_t)Bsz * Cdim * Cdim * 2);     // attn phase
    bf16*  im  = (bf16*)big;                                       // patch phase
    float* peo = (float*)(big + 9633792);
    float* pel = (float*)(big + 9633792 + 19267584);
    float* cf  = (float*)big;                                      // head phase

    // bf16 weight sub-buffers
    const long CC  = (long)Cdim * Cdim;             // 589,824
    const long nCC = (long)Ldim * CC;               // 7,077,888
    const long nMC = (long)Ldim * Mdim * Cdim;      // 28,311,552
    bf16* wqv_bf = wbf;                 // interleaved per layer: [wq CC][wv CC]
    bf16* wk_bf  = wqv_bf + 2 * nCC;
    bf16* wo_bf  = wk_bf + nCC;
    bf16* m1_bf  = wo_bf + nCC;
    bf16* m2_bf  = m1_bf + nMC;
    bf16* pw_bf  = m2_bf + nMC;

    auto cast = [&](const float* src, bf16* dst, long n) {
        cast_f2b<<<dim3((unsigned)((n / 8 + 255) / 256)), 256, 0, stream>>>(src, dst, n);
    };
    cast_qv<<<dim3((unsigned)((2 * nCC / 8 + 255) / 256)), 256, 0, stream>>>(Wq, Wv, wqv_bf);
    cast(Wk, wk_bf, nCC);
    cast(Wo_w, wo_bf, nCC); cast(mlp1_w, m1_bf, nMC); cast(mlp2_w, m2_bf, nMC);
    cast(patch_w, pw_bf, CC);

    // ---------------- patch embedding ----------------
    {
        long tot = (long)PROWS * Cdim;
        im2col_patch<<<dim3((unsigned)((tot + 255) / 256)), 256, 0, stream>>>(x, im);
        gemm_bt<EPI_NONE, true, float><<<dim3(6, 49, 1), 256, 0, stream>>>(
            im, pw_bf, patch_b, peo, PROWS, Cdim, Cdim, 0, 0, 0, 0);
        ln_rows<float><<<dim3(PROWS), 256, 0, stream>>>(peo, pel, pe_g, pe_b);
        long tot2 = (long)TPAD * Cdim;
        assemble_h<<<dim3((unsigned)((tot2 + 255) / 256)), 256, 0, stream>>>(
            pel, cls_tok, pos_enc, h);
    }

    // ---------------- transformer layers ----------------
    const long TNC = (long)NTOKP * Cdim;            // 196,608 per-batch activation stride
    const long QVS = (long)1536 * NTOKP;            // 393,216 per-batch pqvT stride
    for (int l = 0; l < Ldim; ++l) {
        const bf16*  wqv = wqv_bf + (long)l * 2 * CC;
        const bf16*  wk  = wk_bf + (long)l * CC;
        const bf16*  wo  = wo_bf + (long)l * CC;
        const bf16*  m1  = m1_bf + (long)l * Mdim * Cdim;
        const bf16*  m2  = m2_bf + (long)l * Mdim * Cdim;
        const float* wob = Wo_b  + (long)l * Cdim;
        const float* g1  = ln1_g + (long)l * Cdim;
        const float* b1  = ln1_b + (long)l * Cdim;
        const float* g2  = ln2_g + (long)l * Cdim;
        const float* b2  = ln2_b + (long)l * Cdim;
        const float* m1b = mlp1_b + (long)l * Mdim;
        const float* m2b = mlp2_b + (long)l * Cdim;

        ln_rows<bf16><<<dim3(TPAD), 256, 0, stream>>>(h, xn, g1, b1);

        // pqvT[b][c(0..1535)][n] = phi(sum_k wqv[c,k]*xn[b,n,k]); pad cols zeroed
        gemm_bt<EPI_PHI, false, bf16><<<dim3(2, 12, Bsz), 256, 0, stream>>>(
            wqv, xn, nullptr, pqvT, 1536, NTOKP, Cdim, 0, TNC, QVS, NTOK);
        // pk[t][d] = phi(sum_k xn[t,k]*wk[d,k])
        gemm_bt<EPI_PHI, false, bf16><<<dim3(6, TPAD / 128, 1), 256, 0, stream>>>(
            xn, wk, nullptr, pk, TPAD, Cdim, Cdim, 0, 0, 0, 1 << 30);

        // qv[b][c][d] = sum_n pqT[b,c,n]*pvT[b,d,n]
        gemm_bt<EPI_NONE, false, bf16><<<dim3(6, 6, Bsz), 256, 0, stream>>>(
            pqvT, pqvT + (long)768 * NTOKP, nullptr, qv, Cdim, Cdim, NTOKP,
            QVS, QVS, CC, 0);
        // att[b][n][c] = sum_d pk[b,n,d]*qv[b,c,d]
        gemm_bt<EPI_NONE, false, bf16><<<dim3(6, 2, Bsz), 256, 0, stream>>>(
            pk, qv, nullptr, att, NTOKP, Cdim, Cdim, TNC, CC, TNC, 0);
        // h += att @ wo^T + wob
        gemm_bt<EPI_RESID, true, float><<<dim3(6, TPAD / 128, 1), 256, 0, stream>>>(
            att, wo, wob, h, TPAD, Cdim, Cdim, 0, 0, 0, 0);

        ln_rows<bf16><<<dim3(TPAD), 256, 0, stream>>>(h, xn, g2, b2);

        // hid = gelu(xn @ m1^T + m1b)
        gemm_bt<EPI_GELU, true, bf16><<<dim3(Mdim / 128, TPAD / 128, 1), 256, 0, stream>>>(
            xn, m1, m1b, hid, TPAD, Mdim, Cdim, 0, 0, 0, 0);
        // h += hid @ m2^T + m2b
        gemm_bt<EPI_RESID, true, float><<<dim3(6, TPAD / 128, 1), 256, 0, stream>>>(
            hid, m2, m2b, h, TPAD, Cdim, Mdim, 0, 0, 0, 0);
    }

    // ---------------- head ----------------
    cls_pool<<<dim3((Bsz * Cdim + 255) / 256), 256, 0, stream>>>(h, cf);
    head_gemm<<<dim3((Bsz * NCls + 255) / 256), 256, 0, stream>>>(
        cf, head_w, head_b, (float*)d_out);
}

// Round 4
// 3441.682 us; speedup vs baseline: 12.0691x; 1.1391x over previous
//
#include <hip/hip_runtime.h>
#include <hip/hip_bf16.h>
#include <math.h>

// ---------------- model dims ----------------
#define Bsz 32
#define Cdim 768
#define Mdim 3072
#define Ldim 12
#define NTOK 210            // real tokens per image: 14*(14+1)
#define NTOKP 256           // padded tokens per image (div by 128)
#define TPAD (Bsz*NTOKP)    // 8192 padded token rows
#define NPATCH 196
#define PROWS (Bsz*NPATCH)  // 6272 = 49*128
#define NCls 1000

typedef __hip_bfloat16 bf16;
typedef __attribute__((ext_vector_type(8))) short bfrag;   // 8 bf16 = 4 VGPR
typedef __attribute__((ext_vector_type(4))) float f32x4;

enum { EPI_NONE = 0, EPI_PHI = 1, EPI_GELU = 2, EPI_RESID = 3 };

__device__ __forceinline__ void gl_lds16(const void* g, void* l) {
    __builtin_amdgcn_global_load_lds(
        (const __attribute__((address_space(1))) unsigned*)g,
        (__attribute__((address_space(3))) unsigned*)l, 16, 0, 0);
}

__device__ __forceinline__ void stv(float* p, float v) { *p = v; }
__device__ __forceinline__ void stv(bf16* p, float v)  { *p = __float2bfloat16(v); }

// -------------------------------------------------------------------------
// MFMA NT-GEMM, 128x128 tile, BK=32, DEEP PIPELINE:
//   4 LDS slots (64KB), tiles staged 3 ahead via global_load_lds,
//   counted s_waitcnt vmcnt(12/8/4/0) (never 0 in steady state),
//   raw s_barrier (no compiler vmcnt(0) drain), setprio around MFMA.
// T2 LDS swizzle: physical 16B-chunk = logical ^ ((row>>1)&3), applied as
//   linear LDS dest + inverse-swizzled GLOBAL source + swizzled read
//   (rule 21: both-sides-or-neither with global_load_lds).
// Correctness of waits: 4 loads/tile; at step t after issuing stage(t+3),
//   vmcnt(12) => all loads older than the last 3 tiles (t+1,t+2,t+3) have
//   landed => tile t resident. Slot (t+3)&3 was last read at step t-1,
//   whose reads retired before its closing barrier (compiler lgkmcnt
//   before MFMA use) => no WAR hazard.
// C[m,n] = sum_k A[m,k]*B[n,k] (+bias) + epilogue. Batched via blockIdx.z.
// M%128==0, N%128==0, K%32==0, K>=128 guaranteed by caller.
// zc: for EPI_PHI — output cols gn>=zc written as 0 (token pad).
// -------------------------------------------------------------------------
template<int EPI, bool HAS_BIAS, typename OUTT>
__global__ __launch_bounds__(256, 2)
void gemm_bt(const bf16* __restrict__ A, const bf16* __restrict__ B,
             const float* __restrict__ bias, OUTT* __restrict__ C,
             int M, int N, int K, long sA, long sB, long sC, int zc)
{
    // ---- XCD-aware bijective swizzle over the flattened grid (T1/m204) ----
    const int gx = gridDim.x, gy = gridDim.y;
    const int nwg = gx * gy * gridDim.z;
    int flat = (blockIdx.z * gy + blockIdx.y) * gx + blockIdx.x;
    {
        int q8 = nwg >> 3, r8 = nwg & 7;
        int xcd = flat & 7, loc = flat >> 3;
        flat = ((xcd < r8) ? xcd * (q8 + 1) : r8 * (q8 + 1) + (xcd - r8) * q8) + loc;
    }
    const int bx = flat % gx;
    const int tmp = flat / gx;
    const int by = tmp % gy;
    const int bz = tmp / gy;

    A += (long)bz * sA; B += (long)bz * sB; C += (long)bz * sC;
    const int m0 = by * 128, n0 = bx * 128;

    // 4 slots x (A 128x32 + B 128x32) bf16 = 4 x 16KB = 64KB
    __shared__ __align__(16) bf16 sh[4 * 8192];

    const int tid  = threadIdx.x;
    const int lane = tid & 63, wid = tid >> 6;
    const int wr = wid >> 1, wc = wid & 1;
    const int lr = lane & 15, lg = lane >> 4;

    f32x4 acc[4][4];
    #pragma unroll
    for (int i = 0; i < 4; ++i)
        #pragma unroll
        for (int j = 0; j < 4; ++j)
            acc[i][j] = f32x4{0.f, 0.f, 0.f, 0.f};

    // staging source: thread tid covers LDS bytes [tid*16, tid*16+16) of each
    // half-tile (linear dest). Inverse-swizzle the GLOBAL chunk so that the
    // swizzled read below sees logical data: src chunk = (tid&3) ^ ((tid>>3)&3).
    const int srow = tid >> 2;                                   // 0..63
    const int scol = (((tid & 3) ^ ((tid >> 3) & 3))) * 8;       // swizzled 16B chunk
    const bf16* gA = A + (long)(m0 + srow) * K + scol;
    const bf16* gB = B + (long)(n0 + srow) * K + scol;

    // fragment read offsets with T2 swizzle: physical chunk = lg ^ ((lr>>1)&3)
    // (row = wr*64 + lr + i*16 => (row>>1)&3 == (lr>>1)&3 since wr*32,i*8 = 0 mod 4)
    const int axor = (lg ^ ((lr >> 1) & 3)) * 8;
    const int aoff = (wr * 64 + lr) * 32 + axor;
    const int boff = (wc * 64 + lr) * 32 + axor;

    int stage_slot = 0;
    auto stage = [&]() {
        bf16* s = sh + stage_slot * 8192;
        gl_lds16(gA,                s + tid * 8);          // A rows 0-63
        gl_lds16(gA + (long)64 * K, s + 2048 + tid * 8);   // A rows 64-127
        gl_lds16(gB,                s + 4096 + tid * 8);   // B rows 0-63
        gl_lds16(gB + (long)64 * K, s + 6144 + tid * 8);   // B rows 64-127
        gA += 32; gB += 32;
        stage_slot = (stage_slot + 1) & 3;
    };

    const int kt = K >> 5;          // K-steps (>=8 for all call sites)
    stage(); stage(); stage();      // prologue: tiles 0,1,2 in flight

    for (int t = 0; t < kt; ++t) {
        if (t + 3 < kt) stage();    // issue tile t+3 (slot (t+3)&3)

        // counted wait: allow the newest min(3, kt-1-t) tiles to stay in flight
        const int rem = kt - 1 - t;
        if (rem >= 3)      asm volatile("s_waitcnt vmcnt(12)" ::: "memory");
        else if (rem == 2) asm volatile("s_waitcnt vmcnt(8)"  ::: "memory");
        else if (rem == 1) asm volatile("s_waitcnt vmcnt(4)"  ::: "memory");
        else               asm volatile("s_waitcnt vmcnt(0)"  ::: "memory");
        __builtin_amdgcn_s_barrier();       // raw: no compiler vmcnt(0) drain

        const bf16* Ab = sh + (t & 3) * 8192;
        const bf16* Bb = Ab + 4096;
        bfrag a[4], b[4];
        #pragma unroll
        for (int i = 0; i < 4; ++i) a[i] = *(const bfrag*)(Ab + aoff + i * 512);
        #pragma unroll
        for (int j = 0; j < 4; ++j) b[j] = *(const bfrag*)(Bb + boff + j * 512);

        __builtin_amdgcn_s_setprio(1);
        #pragma unroll
        for (int i = 0; i < 4; ++i)
            #pragma unroll
            for (int j = 0; j < 4; ++j)
                acc[i][j] = __builtin_amdgcn_mfma_f32_16x16x32_bf16(a[i], b[j], acc[i][j], 0, 0, 0);
        __builtin_amdgcn_s_setprio(0);
        __builtin_amdgcn_s_barrier();       // reads retired; next stage may overwrite
    }

    // epilogue: C/D mapping col=lane&15, row=(lane>>4)*4+reg  [m89/m91]
    const int cidx  = lane & 15;
    const int rbase = (lane >> 4) * 4;
    #pragma unroll
    for (int i = 0; i < 4; ++i) {
        #pragma unroll
        for (int j = 0; j < 4; ++j) {
            const int gn = n0 + wc * 64 + j * 16 + cidx;
            float bv = HAS_BIAS ? bias[gn] : 0.f;
            #pragma unroll
            for (int r = 0; r < 4; ++r) {
                const int gm = m0 + wr * 64 + i * 16 + rbase + r;
                float v = acc[i][j][r] + bv;
                long idx = (long)gm * N + gn;
                if (EPI == EPI_PHI) {
                    v = (v > 0.f) ? (v + 1.f) : expf(v);
                    if (gn >= zc) v = 0.f;           // zero token-pad cols
                }
                if (EPI == EPI_GELU)  v = 0.5f * v * (1.f + erff(v * 0.70710678118654752f));
                if (EPI == EPI_RESID) v += ((const float*)C)[idx];
                stv(&C[idx], v);
            }
        }
    }
}

// ---------------- LayerNorm over C=768 per row ----------------
template<typename OUTT>
__global__ __launch_bounds__(256)
void ln_rows(const float* __restrict__ x, OUTT* __restrict__ y,
             const float* __restrict__ g, const float* __restrict__ bta)
{
    int r = blockIdx.x;
    const float* xr = x + (long)r * Cdim;
    OUTT* yr = y + (long)r * Cdim;
    int t = threadIdx.x;

    float v0 = xr[t], v1 = xr[t + 256], v2 = xr[t + 512];
    float s  = v0 + v1 + v2;
    float s2 = v0 * v0 + v1 * v1 + v2 * v2;
    #pragma unroll
    for (int o = 32; o > 0; o >>= 1) {
        s  += __shfl_down(s,  o, 64);
        s2 += __shfl_down(s2, o, 64);
    }
    __shared__ float sh[4], sh2[4];
    int wid = t >> 6;
    if ((t & 63) == 0) { sh[wid] = s; sh2[wid] = s2; }
    __syncthreads();
    float S  = sh[0] + sh[1] + sh[2] + sh[3];
    float S2 = sh2[0] + sh2[1] + sh2[2] + sh2[3];
    float mu  = S * (1.f / Cdim);
    float var = S2 * (1.f / Cdim) - mu * mu;
    float inv = rsqrtf(var + 1e-5f);
    stv(&yr[t],       (v0 - mu) * inv * g[t]       + bta[t]);
    stv(&yr[t + 256], (v1 - mu) * inv * g[t + 256] + bta[t + 256]);
    stv(&yr[t + 512], (v2 - mu) * inv * g[t + 512] + bta[t + 512]);
}

// ---------------- fp32 -> bf16 cast (8 elems/thread) ----------------
__global__ void cast_f2b(const float* __restrict__ in, bf16* __restrict__ out, long n)
{
    long i = ((long)blockIdx.x * 256 + threadIdx.x) * 8;
    if (i >= n) return;
    float4 v0 = *(const float4*)(in + i);
    float4 v1 = *(const float4*)(in + i + 4);
    union { bf16 b[8]; uint4 u; } t;
    t.b[0] = __float2bfloat16(v0.x); t.b[1] = __float2bfloat16(v0.y);
    t.b[2] = __float2bfloat16(v0.z); t.b[3] = __float2bfloat16(v0.w);
    t.b[4] = __float2bfloat16(v1.x); t.b[5] = __float2bfloat16(v1.y);
    t.b[6] = __float2bfloat16(v1.z); t.b[7] = __float2bfloat16(v1.w);
    *(uint4*)(out + i) = t.u;
}

// interleaved cast: dst layout per layer l = [Wq(l) CC][Wv(l) CC]
#define CCn (768*768)
__global__ void cast_qv(const float* __restrict__ Wq, const float* __restrict__ Wv,
                        bf16* __restrict__ dst)
{
    long i = ((long)blockIdx.x * 256 + threadIdx.x) * 8;
    if (i >= (long)Ldim * 2 * CCn) return;
    long l = i / (2 * CCn); long rem = i - l * 2 * CCn;
    const float* src = (rem < CCn) ? (Wq + l * CCn + rem) : (Wv + l * CCn + rem - CCn);
    float4 v0 = *(const float4*)(src);
    float4 v1 = *(const float4*)(src + 4);
    union { bf16 b[8]; uint4 u; } t;
    t.b[0] = __float2bfloat16(v0.x); t.b[1] = __float2bfloat16(v0.y);
    t.b[2] = __float2bfloat16(v0.z); t.b[3] = __float2bfloat16(v0.w);
    t.b[4] = __float2bfloat16(v1.x); t.b[5] = __float2bfloat16(v1.y);
    t.b[6] = __float2bfloat16(v1.z); t.b[7] = __float2bfloat16(v1.w);
    *(uint4*)(dst + i) = t.u;
}

// ---------------- im2col (bf16 out) for stride-16 patch conv ----------------
__global__ void im2col_patch(const float* __restrict__ x, bf16* __restrict__ out)
{
    long idx = (long)blockIdx.x * 256 + threadIdx.x;
    if (idx >= (long)PROWS * Cdim) return;
    int col = (int)(idx % Cdim);
    int row = (int)(idx / Cdim);
    int c = col >> 8, rem = col & 255, k = rem >> 4, l = rem & 15;
    int wp = row % 14; int t2 = row / 14; int hp = t2 % 14; int b = t2 / 14;
    out[idx] = __float2bfloat16(x[(((long)b * 3 + c) * 224 + hp * 16 + k) * 224 + wp * 16 + l]);
}

// h[b*256+n, c]: n<210 -> token value + pos_enc; n>=210 -> 0
__global__ void assemble_h(const float* __restrict__ pel,
                           const float* __restrict__ cls_tok,
                           const float* __restrict__ pos_enc,
                           float* __restrict__ h)
{
    long idx = (long)blockIdx.x * 256 + threadIdx.x;
    if (idx >= (long)TPAD * Cdim) return;
    int c = (int)(idx % Cdim);
    long t = idx / Cdim;
    int n = (int)(t % NTOKP); int b = (int)(t / NTOKP);
    if (n >= NTOK) { h[idx] = 0.f; return; }
    int hp = n / 15, w = n % 15;
    float pos = pos_enc[(long)c * NTOK + hp * 15 + w];
    float v = (w == 0) ? cls_tok[c]
                       : pel[((long)b * NPATCH + hp * 14 + (w - 1)) * Cdim + c];
    h[idx] = v + pos;
}

// cls_feat[b,c] = mean_hp h[b*256 + hp*15, c]
__global__ void cls_pool(const float* __restrict__ h, float* __restrict__ cf)
{
    int idx = blockIdx.x * 256 + threadIdx.x;
    if (idx >= Bsz * Cdim) return;
    int c = idx % Cdim, b = idx / Cdim;
    float s = 0.f;
    #pragma unroll
    for (int hp = 0; hp < 14; ++hp)
        s += h[((long)b * NTOKP + hp * 15) * Cdim + c];
    cf[idx] = s * (1.f / 14.f);
}

__global__ void head_gemm(const float* __restrict__ cf, const float* __restrict__ w,
                          const float* __restrict__ bias, float* __restrict__ out)
{
    int idx = blockIdx.x * 256 + threadIdx.x;
    if (idx >= Bsz * NCls) return;
    int j = idx % NCls, b = idx / NCls;
    const float* cr = cf + (long)b * Cdim;
    const float* wr = w + (long)j * Cdim;
    float s = 0.f;
    for (int c = 0; c < Cdim; ++c) s += cr[c] * wr[c];
    out[idx] = s + bias[j];
}

// -------------------------------------------------------------------------
extern "C" void kernel_launch(void* const* d_in, const int* in_sizes, int n_in,
                              void* d_out, int out_size, void* d_ws, size_t ws_size,
                              hipStream_t stream)
{
    const float* x       = (const float*)d_in[0];
    const float* patch_w = (const float*)d_in[1];
    const float* patch_b = (const float*)d_in[2];
    const float* pe_g    = (const float*)d_in[3];
    const float* pe_b    = (const float*)d_in[4];
    const float* cls_tok = (const float*)d_in[5];
    const float* pos_enc = (const float*)d_in[6];
    const float* Wq      = (const float*)d_in[7];
    const float* Wk      = (const float*)d_in[8];
    const float* Wv      = (const float*)d_in[9];
    const float* Wo_w    = (const float*)d_in[10];
    const float* Wo_b    = (const float*)d_in[11];
    const float* ln1_g   = (const float*)d_in[12];
    const float* ln1_b   = (const float*)d_in[13];
    const float* ln2_g   = (const float*)d_in[14];
    const float* ln2_b   = (const float*)d_in[15];
    const float* mlp1_w  = (const float*)d_in[16];
    const float* mlp1_b  = (const float*)d_in[17];
    const float* mlp2_w  = (const float*)d_in[18];
    const float* mlp2_b  = (const float*)d_in[19];
    const float* head_w  = (const float*)d_in[20];
    const float* head_b  = (const float*)d_in[21];

    // ---------------- workspace layout ----------------
    char* base = (char*)d_ws;
    size_t off = 0;
    auto take = [&](size_t bytes) -> char* {
        char* p = base + off; off += (bytes + 255) & ~(size_t)255; return p;
    };
    float* h    = (float*)take((size_t)TPAD * Cdim * 4);           // fp32 residual
    bf16*  xn   = (bf16*) take((size_t)TPAD * Cdim * 2);
    bf16*  pk   = (bf16*) take((size_t)TPAD * Cdim * 2);
    bf16*  pqvT = (bf16*) take((size_t)Bsz * 1536 * NTOKP * 2);    // [B][q0..767,v768..1535][256]
    char*  big  = take((size_t)TPAD * Mdim * 2);                   // 50.3 MB shared region
    bf16*  wbf  = (bf16*) take((size_t)85524480 * 2);              // bf16 weights
    if (off > ws_size) return;

    // big-region aliases (phase-disjoint)
    bf16*  hid = (bf16*)big;                                       // MLP phase
    bf16*  qv  = (bf16*)big;                                       // attn phase [B][768][768]
    bf16*  att = (bf16*)(big + (size_t)Bsz * Cdim * Cdim * 2);     // attn phase
    bf16*  im  = (bf16*)big;                                       // patch phase
    float* peo = (float*)(big + 9633792);
    float* pel = (float*)(big + 9633792 + 19267584);
    float* cf  = (float*)big;                                      // head phase

    // bf16 weight sub-buffers
    const long CC  = (long)Cdim * Cdim;             // 589,824
    const long nCC = (long)Ldim * CC;               // 7,077,888
    const long nMC = (long)Ldim * Mdim * Cdim;      // 28,311,552
    bf16* wqv_bf = wbf;                 // interleaved per layer: [wq CC][wv CC]
    bf16* wk_bf  = wqv_bf + 2 * nCC;
    bf16* wo_bf  = wk_bf + nCC;
    bf16* m1_bf  = wo_bf + nCC;
    bf16* m2_bf  = m1_bf + nMC;
    bf16* pw_bf  = m2_bf + nMC;

    auto cast = [&](const float* src, bf16* dst, long n) {
        cast_f2b<<<dim3((unsigned)((n / 8 + 255) / 256)), 256, 0, stream>>>(src, dst, n);
    };
    cast_qv<<<dim3((unsigned)((2 * nCC / 8 + 255) / 256)), 256, 0, stream>>>(Wq, Wv, wqv_bf);
    cast(Wk, wk_bf, nCC);
    cast(Wo_w, wo_bf, nCC); cast(mlp1_w, m1_bf, nMC); cast(mlp2_w, m2_bf, nMC);
    cast(patch_w, pw_bf, CC);

    // ---------------- patch embedding ----------------
    {
        long tot = (long)PROWS * Cdim;
        im2col_patch<<<dim3((unsigned)((tot + 255) / 256)), 256, 0, stream>>>(x, im);
        gemm_bt<EPI_NONE, true, float><<<dim3(6, 49, 1), 256, 0, stream>>>(
            im, pw_bf, patch_b, peo, PROWS, Cdim, Cdim, 0, 0, 0, 0);
        ln_rows<float><<<dim3(PROWS), 256, 0, stream>>>(peo, pel, pe_g, pe_b);
        long tot2 = (long)TPAD * Cdim;
        assemble_h<<<dim3((unsigned)((tot2 + 255) / 256)), 256, 0, stream>>>(
            pel, cls_tok, pos_enc, h);
    }

    // ---------------- transformer layers ----------------
    const long TNC = (long)NTOKP * Cdim;            // 196,608 per-batch activation stride
    const long QVS = (long)1536 * NTOKP;            // 393,216 per-batch pqvT stride
    for (int l = 0; l < Ldim; ++l) {
        const bf16*  wqv = wqv_bf + (long)l * 2 * CC;
        const bf16*  wk  = wk_bf + (long)l * CC;
        const bf16*  wo  = wo_bf + (long)l * CC;
        const bf16*  m1  = m1_bf + (long)l * Mdim * Cdim;
        const bf16*  m2  = m2_bf + (long)l * Mdim * Cdim;
        const float* wob = Wo_b  + (long)l * Cdim;
        const float* g1  = ln1_g + (long)l * Cdim;
        const float* b1  = ln1_b + (long)l * Cdim;
        const float* g2  = ln2_g + (long)l * Cdim;
        const float* b2  = ln2_b + (long)l * Cdim;
        const float* m1b = mlp1_b + (long)l * Mdim;
        const float* m2b = mlp2_b + (long)l * Cdim;

        ln_rows<bf16><<<dim3(TPAD), 256, 0, stream>>>(h, xn, g1, b1);

        // pqvT[b][c(0..1535)][n] = phi(sum_k wqv[c,k]*xn[b,n,k]); pad cols zeroed
        gemm_bt<EPI_PHI, false, bf16><<<dim3(2, 12, Bsz), 256, 0, stream>>>(
            wqv, xn, nullptr, pqvT, 1536, NTOKP, Cdim, 0, TNC, QVS, NTOK);
        // pk[t][d] = phi(sum_k xn[t,k]*wk[d,k])
        gemm_bt<EPI_PHI, false, bf16><<<dim3(6, TPAD / 128, 1), 256, 0, stream>>>(
            xn, wk, nullptr, pk, TPAD, Cdim, Cdim, 0, 0, 0, 1 << 30);

        // qv[b][c][d] = sum_n pqT[b,c,n]*pvT[b,d,n]
        gemm_bt<EPI_NONE, false, bf16><<<dim3(6, 6, Bsz), 256, 0, stream>>>(
            pqvT, pqvT + (long)768 * NTOKP, nullptr, qv, Cdim, Cdim, NTOKP,
            QVS, QVS, CC, 0);
        // att[b][n][c] = sum_d pk[b,n,d]*qv[b,c,d]
        gemm_bt<EPI_NONE, false, bf16><<<dim3(6, 2, Bsz), 256, 0, stream>>>(
            pk, qv, nullptr, att, NTOKP, Cdim, Cdim, TNC, CC, TNC, 0);
        // h += att @ wo^T + wob
        gemm_bt<EPI_RESID, true, float><<<dim3(6, TPAD / 128, 1), 256, 0, stream>>>(
            att, wo, wob, h, TPAD, Cdim, Cdim, 0, 0, 0, 0);

        ln_rows<bf16><<<dim3(TPAD), 256, 0, stream>>>(h, xn, g2, b2);

        // hid = gelu(xn @ m1^T + m1b)
        gemm_bt<EPI_GELU, true, bf16><<<dim3(Mdim / 128, TPAD / 128, 1), 256, 0, stream>>>(
            xn, m1, m1b, hid, TPAD, Mdim, Cdim, 0, 0, 0, 0);
        // h += hid @ m2^T + m2b
        gemm_bt<EPI_RESID, true, float><<<dim3(6, TPAD / 128, 1), 256, 0, stream>>>(
            hid, m2, m2b, h, TPAD, Cdim, Mdim, 0, 0, 0, 0);
    }

    // ---------------- head ----------------
    cls_pool<<<dim3((Bsz * Cdim + 255) / 256), 256, 0, stream>>>(h, cf);
    head_gemm<<<dim3((Bsz * NCls + 255) / 256), 256, 0, stream>>>(
        cf, head_w, head_b, (float*)d_out);
}